// Round 4
// baseline (88.888 us; speedup 1.0000x reference)
//
#include <hip/hip_runtime.h>
#include <hip/hip_bf16.h>
#include <math.h>

// Problem constants (reference: BATCH=2048, D=256, TEMP=0.5)
#define NB        2048
#define TWO_N     4096
#define DIM       256
#define EPS       1e-12f
#define NT1D      (TWO_N / 128)                 // 32 tile rows/cols
#define NTILES    (NT1D * (NT1D + 1) / 2)       // 528 upper-triangle tiles

typedef __attribute__((ext_vector_type(8))) short  bf16x8;   // 8 bf16 = 4 VGPRs
typedef __attribute__((ext_vector_type(4))) float  f32x4;    // MFMA C/D

// ---------------------------------------------------------------------------
// K1: one wave per PAIR r in [0,2048): L2-normalize emb_i[r] -> z[r] and
// emb_j[r] -> z[r+NB] (bf16), and write the fp32-exact positive dot
// pos[r] = <z_i, z_j>. Also zeroes the scalar output accumulator.
// ---------------------------------------------------------------------------
__global__ __launch_bounds__(256) void nrm_kernel(
    const float* __restrict__ emb_i, const float* __restrict__ emb_j,
    __hip_bfloat16* __restrict__ zb, float* __restrict__ pos,
    float* __restrict__ out)
{
    int t = threadIdx.x;
    int wave = t >> 6, lane = t & 63;
    int r = blockIdx.x * 4 + wave;              // pair index 0..2047
    float4 a = ((const float4*)(emb_i + (size_t)r * DIM))[lane];
    float4 b = ((const float4*)(emb_j + (size_t)r * DIM))[lane];
    float sa = a.x*a.x + a.y*a.y + a.z*a.z + a.w*a.w;
    float sb = b.x*b.x + b.y*b.y + b.z*b.z + b.w*b.w;
    float sd = a.x*b.x + a.y*b.y + a.z*b.z + a.w*b.w;
    #pragma unroll
    for (int off = 32; off >= 1; off >>= 1) {
        sa += __shfl_xor(sa, off, 64);
        sb += __shfl_xor(sb, off, 64);
        sd += __shfl_xor(sd, off, 64);
    }
    float si = 1.0f / fmaxf(sqrtf(sa), EPS);
    float sj = 1.0f / fmaxf(sqrtf(sb), EPS);

    union { __hip_bfloat16 h[4]; uint2 u; } pk;
    pk.h[0] = __float2bfloat16(a.x * si);
    pk.h[1] = __float2bfloat16(a.y * si);
    pk.h[2] = __float2bfloat16(a.z * si);
    pk.h[3] = __float2bfloat16(a.w * si);
    ((uint2*)(zb + (size_t)r * DIM))[lane] = pk.u;
    pk.h[0] = __float2bfloat16(b.x * sj);
    pk.h[1] = __float2bfloat16(b.y * sj);
    pk.h[2] = __float2bfloat16(b.z * sj);
    pk.h[3] = __float2bfloat16(b.w * sj);
    ((uint2*)(zb + (size_t)(r + NB) * DIM))[lane] = pk.u;

    if (lane == 0) pos[r] = sd * si * sj;
    if (blockIdx.x == 0 && t == 0) out[0] = 0.0f;   // loss accumulator
}

// ---------------------------------------------------------------------------
// K2: bf16 MFMA over the 528 upper-triangle 128x128 tiles. NO atomics:
// each wave writes its row/col exp-sums into a private, collision-free slot
// part[stripe][row(0..127)][k(0..63)] (see round-2 comment; unchanged).
//
// K-loop: DEPTH-4 software pipeline. Theory from rounds 1-3: per-wave
// residency ~24us == 64 fragment loads serialized at full latency; the
// (256,3) VGPR cap (~170) forced the allocator to sink loads to their uses
// (round-2 VGPR=72; round-3 naming alone didn't help because the scheduler
// may still sink loads and the cap still binds). Mechanism fix:
//   (a) __launch_bounds__(256,2): 256-VGPR cap (2 waves/SIMD = our actual
//       occupancy: 2 blocks/CU x 4 waves).
//   (b) 4 named fragment sets = 32 loads in flight before the first MFMA.
//   (c) sched_barrier(0) fences so the scheduler cannot sink prefetches.
// Budget: acc 64 + frags 128 + addr/misc ~24 = ~216 VGPR, no spill.
// Fragment layouts (verified m89/m91): A[m=lane&15][k=quad*8+j],
// B[k=quad*8+j][n=lane&15], C/D: col=lane&15, row=quad*4+reg.
// ---------------------------------------------------------------------------
#define MFMA1(Av, Bv, m, n) \
    acc[m][n] = __builtin_amdgcn_mfma_f32_16x16x32_bf16(Av, Bv, acc[m][n], 0, 0, 0);

#define MFMA_ROW(Av, B0v, B1v, B2v, B3v, m) \
    MFMA1(Av, B0v, m, 0) MFMA1(Av, B1v, m, 1) \
    MFMA1(Av, B2v, m, 2) MFMA1(Av, B3v, m, 3)

#define MMSTEP(A0v, A1v, A2v, A3v, B0v, B1v, B2v, B3v) \
    MFMA_ROW(A0v, B0v, B1v, B2v, B3v, 0) \
    MFMA_ROW(A1v, B0v, B1v, B2v, B3v, 1) \
    MFMA_ROW(A2v, B0v, B1v, B2v, B3v, 2) \
    MFMA_ROW(A3v, B0v, B1v, B2v, B3v, 3)

#define LDSET(dA0, dA1, dA2, dA3, dB0, dB1, dB2, dB3, s) \
    dA0 = *(const bf16x8*)(apt0 + (s) * 32); \
    dA1 = *(const bf16x8*)(apt1 + (s) * 32); \
    dA2 = *(const bf16x8*)(apt2 + (s) * 32); \
    dA3 = *(const bf16x8*)(apt3 + (s) * 32); \
    dB0 = *(const bf16x8*)(bpt0 + (s) * 32); \
    dB1 = *(const bf16x8*)(bpt1 + (s) * 32); \
    dB2 = *(const bf16x8*)(bpt2 + (s) * 32); \
    dB3 = *(const bf16x8*)(bpt3 + (s) * 32);

#define SB __builtin_amdgcn_sched_barrier(0);

__global__ __launch_bounds__(256, 2) void simexp_kernel(
    const __hip_bfloat16* __restrict__ zb, float* __restrict__ part)
{
    // Decode linear triangle index -> (bx, by), bx <= by.
    int id = blockIdx.x;
    int by = (int)((sqrtf(8.0f * (float)id + 1.0f) - 1.0f) * 0.5f);
    while ((by + 1) * (by + 2) / 2 <= id) ++by;   // fix float rounding
    while (by * (by + 1) / 2 > id) --by;
    int bx = id - by * (by + 1) / 2;

    const short* Z = (const short*)zb;
    int t = threadIdx.x;
    int w = t >> 6, lane = t & 63;
    int quad = lane >> 4, c16 = lane & 15;
    int wm = w >> 1, wn = w & 1;
    int rbase = bx * 128 + wm * 64;
    int jbase = by * 128 + wn * 64;

    const short* apt0 = Z + (size_t)(rbase +  0 + c16) * DIM + quad * 8;
    const short* apt1 = Z + (size_t)(rbase + 16 + c16) * DIM + quad * 8;
    const short* apt2 = Z + (size_t)(rbase + 32 + c16) * DIM + quad * 8;
    const short* apt3 = Z + (size_t)(rbase + 48 + c16) * DIM + quad * 8;
    const short* bpt0 = Z + (size_t)(jbase +  0 + c16) * DIM + quad * 8;
    const short* bpt1 = Z + (size_t)(jbase + 16 + c16) * DIM + quad * 8;
    const short* bpt2 = Z + (size_t)(jbase + 32 + c16) * DIM + quad * 8;
    const short* bpt3 = Z + (size_t)(jbase + 48 + c16) * DIM + quad * 8;

    f32x4 acc[4][4];
    #pragma unroll
    for (int mt = 0; mt < 4; ++mt)
        #pragma unroll
        for (int nt = 0; nt < 4; ++nt)
            acc[mt][nt] = (f32x4){0.f, 0.f, 0.f, 0.f};

    // Depth-4 pipeline over the 8 K-steps: 4 named sets, 32 loads in flight.
    bf16x8 A0, A1, A2, A3, B0, B1, B2, B3;   // steps 0,4
    bf16x8 P0, P1, P2, P3, Q0, Q1, Q2, Q3;   // steps 1,5
    bf16x8 R0, R1, R2, R3, S0, S1, S2, S3;   // steps 2,6
    bf16x8 U0, U1, U2, U3, V0, V1, V2, V3;   // steps 3,7

    LDSET(A0, A1, A2, A3, B0, B1, B2, B3, 0)
    LDSET(P0, P1, P2, P3, Q0, Q1, Q2, Q3, 1)
    LDSET(R0, R1, R2, R3, S0, S1, S2, S3, 2)
    LDSET(U0, U1, U2, U3, V0, V1, V2, V3, 3)
    SB
    MMSTEP(A0, A1, A2, A3, B0, B1, B2, B3)            // kk=0
    SB
    LDSET(A0, A1, A2, A3, B0, B1, B2, B3, 4)
    SB
    MMSTEP(P0, P1, P2, P3, Q0, Q1, Q2, Q3)            // kk=1
    SB
    LDSET(P0, P1, P2, P3, Q0, Q1, Q2, Q3, 5)
    SB
    MMSTEP(R0, R1, R2, R3, S0, S1, S2, S3)            // kk=2
    SB
    LDSET(R0, R1, R2, R3, S0, S1, S2, S3, 6)
    SB
    MMSTEP(U0, U1, U2, U3, V0, V1, V2, V3)            // kk=3
    SB
    LDSET(U0, U1, U2, U3, V0, V1, V2, V3, 7)
    SB
    MMSTEP(A0, A1, A2, A3, B0, B1, B2, B3)            // kk=4
    MMSTEP(P0, P1, P2, P3, Q0, Q1, Q2, Q3)            // kk=5
    MMSTEP(R0, R1, R2, R3, S0, S1, S2, S3)            // kk=6
    MMSTEP(U0, U1, U2, U3, V0, V1, V2, V3)            // kk=7

    // Epilogue. Row of acc[mt][nt][rg] = rbase+mt*16+quad*4+rg,
    // col = jbase+nt*16+c16.
    float rsum[4][4];
    #pragma unroll
    for (int mt = 0; mt < 4; ++mt)
        #pragma unroll
        for (int rg = 0; rg < 4; ++rg) rsum[mt][rg] = 0.f;

    if (bx == by) {
        // Diagonal block: mask r==j, row-sums only.
        #pragma unroll
        for (int mt = 0; mt < 4; ++mt) {
            #pragma unroll
            for (int nt = 0; nt < 4; ++nt) {
                int j = jbase + nt * 16 + c16;
                #pragma unroll
                for (int rg = 0; rg < 4; ++rg) {
                    int r = rbase + mt * 16 + quad * 4 + rg;
                    float e = __expf(2.0f * acc[mt][nt][rg]);
                    rsum[mt][rg] += (r == j) ? 0.f : e;
                }
            }
        }
    } else {
        // Off-diagonal: no diagonal possible; row-sums AND col-sums.
        float csum[4] = {0.f, 0.f, 0.f, 0.f};
        #pragma unroll
        for (int mt = 0; mt < 4; ++mt) {
            #pragma unroll
            for (int nt = 0; nt < 4; ++nt) {
                #pragma unroll
                for (int rg = 0; rg < 4; ++rg) {
                    float e = __expf(2.0f * acc[mt][nt][rg]);
                    rsum[mt][rg] += e;
                    csum[nt] += e;
                }
            }
        }
        // col c16 of tile nt: sum the 4 quads; quad 0 writes its slot.
        #pragma unroll
        for (int nt = 0; nt < 4; ++nt) {
            float v = csum[nt];
            v += __shfl_xor(v, 16, 64);
            v += __shfl_xor(v, 32, 64);
            if (quad == 0)
                part[(size_t)(by * 128 + wn * 64 + nt * 16 + c16) * 64
                     + 2 * bx + wm] = v;
        }
    }

    // Row-sums: reduce the 16 col-lanes of each quad; c16==0 writes its slot.
    #pragma unroll
    for (int mt = 0; mt < 4; ++mt) {
        #pragma unroll
        for (int rg = 0; rg < 4; ++rg) {
            float v = rsum[mt][rg];
            v += __shfl_xor(v, 1, 64);
            v += __shfl_xor(v, 2, 64);
            v += __shfl_xor(v, 4, 64);
            v += __shfl_xor(v, 8, 64);
            if (c16 == 0)
                part[(size_t)(rbase + mt * 16 + quad * 4 + rg) * 64
                     + 2 * by + wn] = v;
        }
    }
}

// ---------------------------------------------------------------------------
// K3: 32 blocks x 128 threads. Block s, thread t owns row r = s*128+t:
// den_r = sum of its 64 partials (256 B contiguous), then
// loss_r = log(den_r) - 2*pos[r mod 2048]. Block-reduce, one atomicAdd of
// the scaled partial into out[0] (32 atomics total; out zeroed by K1).
// ---------------------------------------------------------------------------
__global__ __launch_bounds__(128) void redloss_kernel(
    const float* __restrict__ part, const float* __restrict__ pos,
    float* __restrict__ out)
{
    int s = blockIdx.x, t = threadIdx.x;
    int r = s * 128 + t;
    const float4* p = (const float4*)(part + ((size_t)r << 6));
    float sum = 0.f;
    #pragma unroll
    for (int i = 0; i < 16; ++i) {
        float4 v = p[i];
        sum += v.x + v.y + v.z + v.w;
    }
    float val = logf(sum) - 2.0f * pos[r & (NB - 1)];
    #pragma unroll
    for (int off = 32; off >= 1; off >>= 1) val += __shfl_xor(val, off, 64);
    __shared__ float red[2];
    if ((t & 63) == 0) red[t >> 6] = val;
    __syncthreads();
    if (t == 0)
        atomicAdd(out, (red[0] + red[1]) * (1.0f / (float)TWO_N));
}

// ---------------------------------------------------------------------------
extern "C" void kernel_launch(void* const* d_in, const int* in_sizes, int n_in,
                              void* d_out, int out_size, void* d_ws, size_t ws_size,
                              hipStream_t stream)
{
    const float* emb_i = (const float*)d_in[0];
    const float* emb_j = (const float*)d_in[1];
    float* out = (float*)d_out;

    __hip_bfloat16* zb = (__hip_bfloat16*)d_ws;           // 4096*256 bf16 = 2 MB
    float* part = (float*)((char*)d_ws + (size_t)TWO_N * DIM * sizeof(__hip_bfloat16));
    // part: 4096 rows x 64 partials = 1 MB
    float* pos = part + (size_t)TWO_N * 64;               // 2048 f32

    nrm_kernel<<<NB / 4, 256, 0, stream>>>(emb_i, emb_j, zb, pos, out);
    simexp_kernel<<<NTILES, 256, 0, stream>>>(zb, part);
    redloss_kernel<<<NT1D, 128, 0, stream>>>(part, pos, out);
}

// Round 5
// 80.224 us; speedup vs baseline: 1.1080x; 1.1080x over previous
//
#include <hip/hip_runtime.h>
#include <hip/hip_bf16.h>
#include <math.h>

// Problem constants (reference: BATCH=2048, D=256, TEMP=0.5)
#define NB        2048
#define TWO_N     4096
#define DIM       256
#define ZSTRIDE   288     // padded zb row stride (bf16 elems) = 576 B.
                          // 512 B (=DIM) keeps addr bits [8:6] constant across
                          // rows -> all 16 lines of a wave fragment-load hit
                          // ONE L2 channel/L1 bank set (16-way serialization,
                          // invariant under r2/r3/r4 pipelining). 576 B = 9
                          // lines/row -> perfect mod-8 channel spread.
#define EPS       1e-12f
#define NT1D      (TWO_N / 128)                 // 32 tile rows/cols
#define NTILES    (NT1D * (NT1D + 1) / 2)       // 528 upper-triangle tiles

typedef __attribute__((ext_vector_type(8))) short  bf16x8;   // 8 bf16 = 4 VGPRs
typedef __attribute__((ext_vector_type(4))) float  f32x4;    // MFMA C/D

// ---------------------------------------------------------------------------
// K1: one wave per PAIR r in [0,2048): L2-normalize emb_i[r] -> z[r] and
// emb_j[r] -> z[r+NB] (bf16, padded stride), and write the fp32-exact
// positive dot pos[r] = <z_i, z_j>. Also zeroes the scalar output.
// ---------------------------------------------------------------------------
__global__ __launch_bounds__(256) void nrm_kernel(
    const float* __restrict__ emb_i, const float* __restrict__ emb_j,
    __hip_bfloat16* __restrict__ zb, float* __restrict__ pos,
    float* __restrict__ out)
{
    int t = threadIdx.x;
    int wave = t >> 6, lane = t & 63;
    int r = blockIdx.x * 4 + wave;              // pair index 0..2047
    float4 a = ((const float4*)(emb_i + (size_t)r * DIM))[lane];
    float4 b = ((const float4*)(emb_j + (size_t)r * DIM))[lane];
    float sa = a.x*a.x + a.y*a.y + a.z*a.z + a.w*a.w;
    float sb = b.x*b.x + b.y*b.y + b.z*b.z + b.w*b.w;
    float sd = a.x*b.x + a.y*b.y + a.z*b.z + a.w*b.w;
    #pragma unroll
    for (int off = 32; off >= 1; off >>= 1) {
        sa += __shfl_xor(sa, off, 64);
        sb += __shfl_xor(sb, off, 64);
        sd += __shfl_xor(sd, off, 64);
    }
    float si = 1.0f / fmaxf(sqrtf(sa), EPS);
    float sj = 1.0f / fmaxf(sqrtf(sb), EPS);

    union { __hip_bfloat16 h[4]; uint2 u; } pk;
    pk.h[0] = __float2bfloat16(a.x * si);
    pk.h[1] = __float2bfloat16(a.y * si);
    pk.h[2] = __float2bfloat16(a.z * si);
    pk.h[3] = __float2bfloat16(a.w * si);
    ((uint2*)(zb + (size_t)r * ZSTRIDE))[lane] = pk.u;
    pk.h[0] = __float2bfloat16(b.x * sj);
    pk.h[1] = __float2bfloat16(b.y * sj);
    pk.h[2] = __float2bfloat16(b.z * sj);
    pk.h[3] = __float2bfloat16(b.w * sj);
    ((uint2*)(zb + (size_t)(r + NB) * ZSTRIDE))[lane] = pk.u;

    if (lane == 0) pos[r] = sd * si * sj;
    if (blockIdx.x == 0 && t == 0) out[0] = 0.0f;   // loss accumulator
}

// ---------------------------------------------------------------------------
// K2: bf16 MFMA over the 528 upper-triangle 128x128 tiles. NO atomics:
// each wave writes its row/col exp-sums into a private, collision-free slot
// part[stripe][row(0..127)][k(0..63)] (see round-2 comment; unchanged).
// K-loop: depth-4 named-register software pipeline (r4 structure), reading
// zb at the PADDED 576-B row stride to kill the L2-channel conflict.
// Fragment layouts (verified m89/m91): A[m=lane&15][k=quad*8+j],
// B[k=quad*8+j][n=lane&15], C/D: col=lane&15, row=quad*4+reg.
// ---------------------------------------------------------------------------
#define MFMA1(Av, Bv, m, n) \
    acc[m][n] = __builtin_amdgcn_mfma_f32_16x16x32_bf16(Av, Bv, acc[m][n], 0, 0, 0);

#define MFMA_ROW(Av, B0v, B1v, B2v, B3v, m) \
    MFMA1(Av, B0v, m, 0) MFMA1(Av, B1v, m, 1) \
    MFMA1(Av, B2v, m, 2) MFMA1(Av, B3v, m, 3)

#define MMSTEP(A0v, A1v, A2v, A3v, B0v, B1v, B2v, B3v) \
    MFMA_ROW(A0v, B0v, B1v, B2v, B3v, 0) \
    MFMA_ROW(A1v, B0v, B1v, B2v, B3v, 1) \
    MFMA_ROW(A2v, B0v, B1v, B2v, B3v, 2) \
    MFMA_ROW(A3v, B0v, B1v, B2v, B3v, 3)

#define LDSET(dA0, dA1, dA2, dA3, dB0, dB1, dB2, dB3, s) \
    dA0 = *(const bf16x8*)(apt0 + (s) * 32); \
    dA1 = *(const bf16x8*)(apt1 + (s) * 32); \
    dA2 = *(const bf16x8*)(apt2 + (s) * 32); \
    dA3 = *(const bf16x8*)(apt3 + (s) * 32); \
    dB0 = *(const bf16x8*)(bpt0 + (s) * 32); \
    dB1 = *(const bf16x8*)(bpt1 + (s) * 32); \
    dB2 = *(const bf16x8*)(bpt2 + (s) * 32); \
    dB3 = *(const bf16x8*)(bpt3 + (s) * 32);

#define SB __builtin_amdgcn_sched_barrier(0);

__global__ __launch_bounds__(256, 2) void simexp_kernel(
    const __hip_bfloat16* __restrict__ zb, float* __restrict__ part)
{
    // Decode linear triangle index -> (bx, by), bx <= by.
    int id = blockIdx.x;
    int by = (int)((sqrtf(8.0f * (float)id + 1.0f) - 1.0f) * 0.5f);
    while ((by + 1) * (by + 2) / 2 <= id) ++by;   // fix float rounding
    while (by * (by + 1) / 2 > id) --by;
    int bx = id - by * (by + 1) / 2;

    const short* Z = (const short*)zb;
    int t = threadIdx.x;
    int w = t >> 6, lane = t & 63;
    int quad = lane >> 4, c16 = lane & 15;
    int wm = w >> 1, wn = w & 1;
    int rbase = bx * 128 + wm * 64;
    int jbase = by * 128 + wn * 64;

    const short* apt0 = Z + (size_t)(rbase +  0 + c16) * ZSTRIDE + quad * 8;
    const short* apt1 = Z + (size_t)(rbase + 16 + c16) * ZSTRIDE + quad * 8;
    const short* apt2 = Z + (size_t)(rbase + 32 + c16) * ZSTRIDE + quad * 8;
    const short* apt3 = Z + (size_t)(rbase + 48 + c16) * ZSTRIDE + quad * 8;
    const short* bpt0 = Z + (size_t)(jbase +  0 + c16) * ZSTRIDE + quad * 8;
    const short* bpt1 = Z + (size_t)(jbase + 16 + c16) * ZSTRIDE + quad * 8;
    const short* bpt2 = Z + (size_t)(jbase + 32 + c16) * ZSTRIDE + quad * 8;
    const short* bpt3 = Z + (size_t)(jbase + 48 + c16) * ZSTRIDE + quad * 8;

    f32x4 acc[4][4];
    #pragma unroll
    for (int mt = 0; mt < 4; ++mt)
        #pragma unroll
        for (int nt = 0; nt < 4; ++nt)
            acc[mt][nt] = (f32x4){0.f, 0.f, 0.f, 0.f};

    // Depth-4 pipeline over the 8 K-steps: 4 named sets, 32 loads in flight.
    bf16x8 A0, A1, A2, A3, B0, B1, B2, B3;   // steps 0,4
    bf16x8 P0, P1, P2, P3, Q0, Q1, Q2, Q3;   // steps 1,5
    bf16x8 R0, R1, R2, R3, S0, S1, S2, S3;   // steps 2,6
    bf16x8 U0, U1, U2, U3, V0, V1, V2, V3;   // steps 3,7

    LDSET(A0, A1, A2, A3, B0, B1, B2, B3, 0)
    LDSET(P0, P1, P2, P3, Q0, Q1, Q2, Q3, 1)
    LDSET(R0, R1, R2, R3, S0, S1, S2, S3, 2)
    LDSET(U0, U1, U2, U3, V0, V1, V2, V3, 3)
    SB
    MMSTEP(A0, A1, A2, A3, B0, B1, B2, B3)            // kk=0
    SB
    LDSET(A0, A1, A2, A3, B0, B1, B2, B3, 4)
    SB
    MMSTEP(P0, P1, P2, P3, Q0, Q1, Q2, Q3)            // kk=1
    SB
    LDSET(P0, P1, P2, P3, Q0, Q1, Q2, Q3, 5)
    SB
    MMSTEP(R0, R1, R2, R3, S0, S1, S2, S3)            // kk=2
    SB
    LDSET(R0, R1, R2, R3, S0, S1, S2, S3, 6)
    SB
    MMSTEP(U0, U1, U2, U3, V0, V1, V2, V3)            // kk=3
    SB
    LDSET(U0, U1, U2, U3, V0, V1, V2, V3, 7)
    SB
    MMSTEP(A0, A1, A2, A3, B0, B1, B2, B3)            // kk=4
    MMSTEP(P0, P1, P2, P3, Q0, Q1, Q2, Q3)            // kk=5
    MMSTEP(R0, R1, R2, R3, S0, S1, S2, S3)            // kk=6
    MMSTEP(U0, U1, U2, U3, V0, V1, V2, V3)            // kk=7

    // Epilogue. Row of acc[mt][nt][rg] = rbase+mt*16+quad*4+rg,
    // col = jbase+nt*16+c16.
    float rsum[4][4];
    #pragma unroll
    for (int mt = 0; mt < 4; ++mt)
        #pragma unroll
        for (int rg = 0; rg < 4; ++rg) rsum[mt][rg] = 0.f;

    if (bx == by) {
        // Diagonal block: mask r==j, row-sums only.
        #pragma unroll
        for (int mt = 0; mt < 4; ++mt) {
            #pragma unroll
            for (int nt = 0; nt < 4; ++nt) {
                int j = jbase + nt * 16 + c16;
                #pragma unroll
                for (int rg = 0; rg < 4; ++rg) {
                    int r = rbase + mt * 16 + quad * 4 + rg;
                    float e = __expf(2.0f * acc[mt][nt][rg]);
                    rsum[mt][rg] += (r == j) ? 0.f : e;
                }
            }
        }
    } else {
        // Off-diagonal: no diagonal possible; row-sums AND col-sums.
        float csum[4] = {0.f, 0.f, 0.f, 0.f};
        #pragma unroll
        for (int mt = 0; mt < 4; ++mt) {
            #pragma unroll
            for (int nt = 0; nt < 4; ++nt) {
                #pragma unroll
                for (int rg = 0; rg < 4; ++rg) {
                    float e = __expf(2.0f * acc[mt][nt][rg]);
                    rsum[mt][rg] += e;
                    csum[nt] += e;
                }
            }
        }
        // col c16 of tile nt: sum the 4 quads; quad 0 writes its slot.
        #pragma unroll
        for (int nt = 0; nt < 4; ++nt) {
            float v = csum[nt];
            v += __shfl_xor(v, 16, 64);
            v += __shfl_xor(v, 32, 64);
            if (quad == 0)
                part[(size_t)(by * 128 + wn * 64 + nt * 16 + c16) * 64
                     + 2 * bx + wm] = v;
        }
    }

    // Row-sums: reduce the 16 col-lanes of each quad; c16==0 writes its slot.
    #pragma unroll
    for (int mt = 0; mt < 4; ++mt) {
        #pragma unroll
        for (int rg = 0; rg < 4; ++rg) {
            float v = rsum[mt][rg];
            v += __shfl_xor(v, 1, 64);
            v += __shfl_xor(v, 2, 64);
            v += __shfl_xor(v, 4, 64);
            v += __shfl_xor(v, 8, 64);
            if (c16 == 0)
                part[(size_t)(rbase + mt * 16 + quad * 4 + rg) * 64
                     + 2 * by + wn] = v;
        }
    }
}

// ---------------------------------------------------------------------------
// K3: 32 blocks x 128 threads. Block s, thread t owns row r = s*128+t:
// den_r = sum of its 64 partials (256 B contiguous), then
// loss_r = log(den_r) - 2*pos[r mod 2048]. Block-reduce, one atomicAdd of
// the scaled partial into out[0] (32 atomics total; out zeroed by K1).
// ---------------------------------------------------------------------------
__global__ __launch_bounds__(128) void redloss_kernel(
    const float* __restrict__ part, const float* __restrict__ pos,
    float* __restrict__ out)
{
    int s = blockIdx.x, t = threadIdx.x;
    int r = s * 128 + t;
    const float4* p = (const float4*)(part + ((size_t)r << 6));
    float sum = 0.f;
    #pragma unroll
    for (int i = 0; i < 16; ++i) {
        float4 v = p[i];
        sum += v.x + v.y + v.z + v.w;
    }
    float val = logf(sum) - 2.0f * pos[r & (NB - 1)];
    #pragma unroll
    for (int off = 32; off >= 1; off >>= 1) val += __shfl_xor(val, off, 64);
    __shared__ float red[2];
    if ((t & 63) == 0) red[t >> 6] = val;
    __syncthreads();
    if (t == 0)
        atomicAdd(out, (red[0] + red[1]) * (1.0f / (float)TWO_N));
}

// ---------------------------------------------------------------------------
extern "C" void kernel_launch(void* const* d_in, const int* in_sizes, int n_in,
                              void* d_out, int out_size, void* d_ws, size_t ws_size,
                              hipStream_t stream)
{
    const float* emb_i = (const float*)d_in[0];
    const float* emb_j = (const float*)d_in[1];
    float* out = (float*)d_out;

    __hip_bfloat16* zb = (__hip_bfloat16*)d_ws;           // 4096*288 bf16 = 2.25 MB
    float* part = (float*)((char*)d_ws + (size_t)TWO_N * ZSTRIDE * sizeof(__hip_bfloat16));
    // part: 4096 rows x 64 partials = 1 MB
    float* pos = part + (size_t)TWO_N * 64;               // 2048 f32

    nrm_kernel<<<NB / 4, 256, 0, stream>>>(emb_i, emb_j, zb, pos, out);
    simexp_kernel<<<NTILES, 256, 0, stream>>>(zb, part);
    redloss_kernel<<<NT1D, 128, 0, stream>>>(part, pos, out);
}

// Round 6
// 77.385 us; speedup vs baseline: 1.1486x; 1.0367x over previous
//
#include <hip/hip_runtime.h>
#include <hip/hip_bf16.h>
#include <math.h>

// Problem constants (reference: BATCH=2048, D=256, TEMP=0.5)
#define NB        2048
#define TWO_N     4096
#define DIM       256
#define EPS       1e-12f
#define NT1D      (TWO_N / 128)                 // 32 tile rows/cols
#define NTILES    (NT1D * (NT1D + 1) / 2)       // 528 upper-triangle tiles

// z storage: FRAGMENT-MAJOR tiled layout. For row R, element e:
//   short_idx = (R>>4)*4096 + (e>>5)*512 + ((e>>3)&3)*128 + (R&15)*8 + (e&7)
// (16-row block region = 4096 shorts = 8 KB; piece = 8 bf16 = 16 B.)
// Why: the MFMA A/B fragment for (row-block, K-step s) then sits at
//   base + s*512 + lane*8   (lane = quad*16 + c16)
// i.e. every fragment load is a CONTIGUOUS 1-KB wave-load (lane i -> base
// + i*16 B, 16 adjacent lines). Rounds 2-4 proved the old scattered loads
// (16 lines at 512/576-B stride per instruction) are schedule-invariantly
// slow (~25us in simexp); contiguity is the m13-proven fast pattern.

typedef __attribute__((ext_vector_type(8))) short  bf16x8;   // 8 bf16 = 4 VGPRs
typedef __attribute__((ext_vector_type(4))) float  f32x4;    // MFMA C/D

// ---------------------------------------------------------------------------
// K1: one wave per PAIR r in [0,2048): L2-normalize emb_i[r] -> z[r] and
// emb_j[r] -> z[r+NB] (bf16, fragment-major layout), and write the
// fp32-exact positive dot pos[r] = <z_i, z_j>. Also zeroes the output.
// Lane l holds elements e = 4l..4l+3 -> piece (kk=l>>3, quad=(l>>1)&3),
// half (l&1): dst = (R>>4)*4096 + (l>>3)*512 + ((l>>1)&3)*128 + (R&15)*8
//             + (l&1)*4   (8-B store).
// ---------------------------------------------------------------------------
__global__ __launch_bounds__(256) void nrm_kernel(
    const float* __restrict__ emb_i, const float* __restrict__ emb_j,
    short* __restrict__ zt, float* __restrict__ pos,
    float* __restrict__ out)
{
    int t = threadIdx.x;
    int wave = t >> 6, lane = t & 63;
    int r = blockIdx.x * 4 + wave;              // pair index 0..2047
    float4 a = ((const float4*)(emb_i + (size_t)r * DIM))[lane];
    float4 b = ((const float4*)(emb_j + (size_t)r * DIM))[lane];
    float sa = a.x*a.x + a.y*a.y + a.z*a.z + a.w*a.w;
    float sb = b.x*b.x + b.y*b.y + b.z*b.z + b.w*b.w;
    float sd = a.x*b.x + a.y*b.y + a.z*b.z + a.w*b.w;
    #pragma unroll
    for (int off = 32; off >= 1; off >>= 1) {
        sa += __shfl_xor(sa, off, 64);
        sb += __shfl_xor(sb, off, 64);
        sd += __shfl_xor(sd, off, 64);
    }
    float si = 1.0f / fmaxf(sqrtf(sa), EPS);
    float sj = 1.0f / fmaxf(sqrtf(sb), EPS);

    int dst = (r >> 4) * 4096 + (lane >> 3) * 512 + ((lane >> 1) & 3) * 128
            + (r & 15) * 8 + (lane & 1) * 4;

    union { __hip_bfloat16 h[4]; uint2 u; } pk;
    pk.h[0] = __float2bfloat16(a.x * si);
    pk.h[1] = __float2bfloat16(a.y * si);
    pk.h[2] = __float2bfloat16(a.z * si);
    pk.h[3] = __float2bfloat16(a.w * si);
    *(uint2*)(zt + dst) = pk.u;                       // z_i row r
    pk.h[0] = __float2bfloat16(b.x * sj);
    pk.h[1] = __float2bfloat16(b.y * sj);
    pk.h[2] = __float2bfloat16(b.z * sj);
    pk.h[3] = __float2bfloat16(b.w * sj);
    *(uint2*)(zt + dst + 128 * 4096) = pk.u;          // z_j row r+2048

    if (lane == 0) pos[r] = sd * si * sj;
    if (blockIdx.x == 0 && t == 0) out[0] = 0.0f;     // loss accumulator
}

// ---------------------------------------------------------------------------
// K2: bf16 MFMA over the 528 upper-triangle 128x128 tiles. NO atomics:
// each wave writes its row/col exp-sums into a private, collision-free slot
// part[stripe][row(0..127)][k(0..63)] (see round-2 comment; unchanged).
// K-loop: depth-4 named-register pipeline (r4); fragment loads are now
// contiguous 1-KB wave-loads from the fragment-major z layout.
// Fragment layouts (verified m89/m91): A[m=lane&15][k=quad*8+j],
// B[k=quad*8+j][n=lane&15], C/D: col=lane&15, row=quad*4+reg.
// ---------------------------------------------------------------------------
#define MFMA1(Av, Bv, m, n) \
    acc[m][n] = __builtin_amdgcn_mfma_f32_16x16x32_bf16(Av, Bv, acc[m][n], 0, 0, 0);

#define MFMA_ROW(Av, B0v, B1v, B2v, B3v, m) \
    MFMA1(Av, B0v, m, 0) MFMA1(Av, B1v, m, 1) \
    MFMA1(Av, B2v, m, 2) MFMA1(Av, B3v, m, 3)

#define MMSTEP(A0v, A1v, A2v, A3v, B0v, B1v, B2v, B3v) \
    MFMA_ROW(A0v, B0v, B1v, B2v, B3v, 0) \
    MFMA_ROW(A1v, B0v, B1v, B2v, B3v, 1) \
    MFMA_ROW(A2v, B0v, B1v, B2v, B3v, 2) \
    MFMA_ROW(A3v, B0v, B1v, B2v, B3v, 3)

#define LDSET(dA0, dA1, dA2, dA3, dB0, dB1, dB2, dB3, s) \
    dA0 = *(const bf16x8*)(apt0 + (s) * 512); \
    dA1 = *(const bf16x8*)(apt1 + (s) * 512); \
    dA2 = *(const bf16x8*)(apt2 + (s) * 512); \
    dA3 = *(const bf16x8*)(apt3 + (s) * 512); \
    dB0 = *(const bf16x8*)(bpt0 + (s) * 512); \
    dB1 = *(const bf16x8*)(bpt1 + (s) * 512); \
    dB2 = *(const bf16x8*)(bpt2 + (s) * 512); \
    dB3 = *(const bf16x8*)(bpt3 + (s) * 512);

#define SB __builtin_amdgcn_sched_barrier(0);

__global__ __launch_bounds__(256, 2) void simexp_kernel(
    const short* __restrict__ zt, float* __restrict__ part)
{
    // Decode linear triangle index -> (bx, by), bx <= by.
    int id = blockIdx.x;
    int by = (int)((sqrtf(8.0f * (float)id + 1.0f) - 1.0f) * 0.5f);
    while ((by + 1) * (by + 2) / 2 <= id) ++by;   // fix float rounding
    while (by * (by + 1) / 2 > id) --by;
    int bx = id - by * (by + 1) / 2;

    const short* Z = zt;
    int t = threadIdx.x;
    int w = t >> 6, lane = t & 63;
    int quad = lane >> 4, c16 = lane & 15;
    int wm = w >> 1, wn = w & 1;
    int rbase = bx * 128 + wm * 64;
    int jbase = by * 128 + wn * 64;

    // Fragment bases: row-block (rbase>>4)+mt, contiguous lane*8 shorts.
    const short* apt0 = Z + (size_t)((rbase >> 4) + 0) * 4096 + lane * 8;
    const short* apt1 = Z + (size_t)((rbase >> 4) + 1) * 4096 + lane * 8;
    const short* apt2 = Z + (size_t)((rbase >> 4) + 2) * 4096 + lane * 8;
    const short* apt3 = Z + (size_t)((rbase >> 4) + 3) * 4096 + lane * 8;
    const short* bpt0 = Z + (size_t)((jbase >> 4) + 0) * 4096 + lane * 8;
    const short* bpt1 = Z + (size_t)((jbase >> 4) + 1) * 4096 + lane * 8;
    const short* bpt2 = Z + (size_t)((jbase >> 4) + 2) * 4096 + lane * 8;
    const short* bpt3 = Z + (size_t)((jbase >> 4) + 3) * 4096 + lane * 8;

    f32x4 acc[4][4];
    #pragma unroll
    for (int mt = 0; mt < 4; ++mt)
        #pragma unroll
        for (int nt = 0; nt < 4; ++nt)
            acc[mt][nt] = (f32x4){0.f, 0.f, 0.f, 0.f};

    // Depth-4 pipeline over the 8 K-steps: 4 named sets, 32 loads in flight.
    bf16x8 A0, A1, A2, A3, B0, B1, B2, B3;   // steps 0,4
    bf16x8 P0, P1, P2, P3, Q0, Q1, Q2, Q3;   // steps 1,5
    bf16x8 R0, R1, R2, R3, S0, S1, S2, S3;   // steps 2,6
    bf16x8 U0, U1, U2, U3, V0, V1, V2, V3;   // steps 3,7

    LDSET(A0, A1, A2, A3, B0, B1, B2, B3, 0)
    LDSET(P0, P1, P2, P3, Q0, Q1, Q2, Q3, 1)
    LDSET(R0, R1, R2, R3, S0, S1, S2, S3, 2)
    LDSET(U0, U1, U2, U3, V0, V1, V2, V3, 3)
    SB
    MMSTEP(A0, A1, A2, A3, B0, B1, B2, B3)            // kk=0
    SB
    LDSET(A0, A1, A2, A3, B0, B1, B2, B3, 4)
    SB
    MMSTEP(P0, P1, P2, P3, Q0, Q1, Q2, Q3)            // kk=1
    SB
    LDSET(P0, P1, P2, P3, Q0, Q1, Q2, Q3, 5)
    SB
    MMSTEP(R0, R1, R2, R3, S0, S1, S2, S3)            // kk=2
    SB
    LDSET(R0, R1, R2, R3, S0, S1, S2, S3, 6)
    SB
    MMSTEP(U0, U1, U2, U3, V0, V1, V2, V3)            // kk=3
    SB
    LDSET(U0, U1, U2, U3, V0, V1, V2, V3, 7)
    SB
    MMSTEP(A0, A1, A2, A3, B0, B1, B2, B3)            // kk=4
    MMSTEP(P0, P1, P2, P3, Q0, Q1, Q2, Q3)            // kk=5
    MMSTEP(R0, R1, R2, R3, S0, S1, S2, S3)            // kk=6
    MMSTEP(U0, U1, U2, U3, V0, V1, V2, V3)            // kk=7

    // Epilogue. Row of acc[mt][nt][rg] = rbase+mt*16+quad*4+rg,
    // col = jbase+nt*16+c16.
    float rsum[4][4];
    #pragma unroll
    for (int mt = 0; mt < 4; ++mt)
        #pragma unroll
        for (int rg = 0; rg < 4; ++rg) rsum[mt][rg] = 0.f;

    if (bx == by) {
        // Diagonal block: mask r==j, row-sums only.
        #pragma unroll
        for (int mt = 0; mt < 4; ++mt) {
            #pragma unroll
            for (int nt = 0; nt < 4; ++nt) {
                int j = jbase + nt * 16 + c16;
                #pragma unroll
                for (int rg = 0; rg < 4; ++rg) {
                    int r = rbase + mt * 16 + quad * 4 + rg;
                    float e = __expf(2.0f * acc[mt][nt][rg]);
                    rsum[mt][rg] += (r == j) ? 0.f : e;
                }
            }
        }
    } else {
        // Off-diagonal: no diagonal possible; row-sums AND col-sums.
        float csum[4] = {0.f, 0.f, 0.f, 0.f};
        #pragma unroll
        for (int mt = 0; mt < 4; ++mt) {
            #pragma unroll
            for (int nt = 0; nt < 4; ++nt) {
                #pragma unroll
                for (int rg = 0; rg < 4; ++rg) {
                    float e = __expf(2.0f * acc[mt][nt][rg]);
                    rsum[mt][rg] += e;
                    csum[nt] += e;
                }
            }
        }
        // col c16 of tile nt: sum the 4 quads; quad 0 writes its slot.
        #pragma unroll
        for (int nt = 0; nt < 4; ++nt) {
            float v = csum[nt];
            v += __shfl_xor(v, 16, 64);
            v += __shfl_xor(v, 32, 64);
            if (quad == 0)
                part[(size_t)(by * 128 + wn * 64 + nt * 16 + c16) * 64
                     + 2 * bx + wm] = v;
        }
    }

    // Row-sums: reduce the 16 col-lanes of each quad; c16==0 writes its slot.
    #pragma unroll
    for (int mt = 0; mt < 4; ++mt) {
        #pragma unroll
        for (int rg = 0; rg < 4; ++rg) {
            float v = rsum[mt][rg];
            v += __shfl_xor(v, 1, 64);
            v += __shfl_xor(v, 2, 64);
            v += __shfl_xor(v, 4, 64);
            v += __shfl_xor(v, 8, 64);
            if (c16 == 0)
                part[(size_t)(rbase + mt * 16 + quad * 4 + rg) * 64
                     + 2 * by + wn] = v;
        }
    }
}

// ---------------------------------------------------------------------------
// K3: 32 blocks x 128 threads. Block s, thread t owns row r = s*128+t:
// den_r = sum of its 64 partials (256 B contiguous), then
// loss_r = log(den_r) - 2*pos[r mod 2048]. Block-reduce, one atomicAdd of
// the scaled partial into out[0] (32 atomics total; out zeroed by K1).
// ---------------------------------------------------------------------------
__global__ __launch_bounds__(128) void redloss_kernel(
    const float* __restrict__ part, const float* __restrict__ pos,
    float* __restrict__ out)
{
    int s = blockIdx.x, t = threadIdx.x;
    int r = s * 128 + t;
    const float4* p = (const float4*)(part + ((size_t)r << 6));
    float sum = 0.f;
    #pragma unroll
    for (int i = 0; i < 16; ++i) {
        float4 v = p[i];
        sum += v.x + v.y + v.z + v.w;
    }
    float val = logf(sum) - 2.0f * pos[r & (NB - 1)];
    #pragma unroll
    for (int off = 32; off >= 1; off >>= 1) val += __shfl_xor(val, off, 64);
    __shared__ float red[2];
    if ((t & 63) == 0) red[t >> 6] = val;
    __syncthreads();
    if (t == 0)
        atomicAdd(out, (red[0] + red[1]) * (1.0f / (float)TWO_N));
}

// ---------------------------------------------------------------------------
extern "C" void kernel_launch(void* const* d_in, const int* in_sizes, int n_in,
                              void* d_out, int out_size, void* d_ws, size_t ws_size,
                              hipStream_t stream)
{
    const float* emb_i = (const float*)d_in[0];
    const float* emb_j = (const float*)d_in[1];
    float* out = (float*)d_out;

    short* zt = (short*)d_ws;                             // 4096*256 bf16 = 2 MB (tiled)
    float* part = (float*)((char*)d_ws + (size_t)TWO_N * DIM * sizeof(short));
    // part: 4096 rows x 64 partials = 1 MB
    float* pos = part + (size_t)TWO_N * 64;               // 2048 f32

    nrm_kernel<<<NB / 4, 256, 0, stream>>>(emb_i, emb_j, zt, pos, out);
    simexp_kernel<<<NTILES, 256, 0, stream>>>(zt, part);
    redloss_kernel<<<NT1D, 128, 0, stream>>>(part, pos, out);
}

// Round 7
// 76.886 us; speedup vs baseline: 1.1561x; 1.0065x over previous
//
#include <hip/hip_runtime.h>
#include <hip/hip_bf16.h>
#include <math.h>

// Problem constants (reference: BATCH=2048, D=256, TEMP=0.5)
#define NB        2048
#define TWO_N     4096
#define DIM       256
#define EPS       1e-12f
#define NT1D      (TWO_N / 128)                 // 32 tile rows/cols
#define NTILES    (NT1D * (NT1D + 1) / 2)       // 528 upper-triangle tiles

// z storage: FRAGMENT-MAJOR tiled layout (r6). For row R, element e:
//   short_idx = (R>>4)*4096 + (e>>5)*512 + ((e>>3)&3)*128 + (R&15)*8 + (e&7)
// A (row-block RB, K-step s) fragment piece = 1 KB contiguous at
// RB*4096 + s*512; lane l's 16 B at +l*8 shorts.

typedef __attribute__((ext_vector_type(8))) short  bf16x8;   // 8 bf16 = 4 VGPRs
typedef __attribute__((ext_vector_type(4))) float  f32x4;    // MFMA C/D

// ---------------------------------------------------------------------------
// K1: one wave per PAIR r in [0,2048): L2-normalize emb_i[r] -> z[r] and
// emb_j[r] -> z[r+NB] (bf16, fragment-major layout), and write the
// fp32-exact positive dot pos[r] = <z_i, z_j>. Also zeroes the output.
// ---------------------------------------------------------------------------
__global__ __launch_bounds__(256) void nrm_kernel(
    const float* __restrict__ emb_i, const float* __restrict__ emb_j,
    short* __restrict__ zt, float* __restrict__ pos,
    float* __restrict__ out)
{
    int t = threadIdx.x;
    int wave = t >> 6, lane = t & 63;
    int r = blockIdx.x * 4 + wave;              // pair index 0..2047
    float4 a = ((const float4*)(emb_i + (size_t)r * DIM))[lane];
    float4 b = ((const float4*)(emb_j + (size_t)r * DIM))[lane];
    float sa = a.x*a.x + a.y*a.y + a.z*a.z + a.w*a.w;
    float sb = b.x*b.x + b.y*b.y + b.z*b.z + b.w*b.w;
    float sd = a.x*b.x + a.y*b.y + a.z*b.z + a.w*b.w;
    #pragma unroll
    for (int off = 32; off >= 1; off >>= 1) {
        sa += __shfl_xor(sa, off, 64);
        sb += __shfl_xor(sb, off, 64);
        sd += __shfl_xor(sd, off, 64);
    }
    float si = 1.0f / fmaxf(sqrtf(sa), EPS);
    float sj = 1.0f / fmaxf(sqrtf(sb), EPS);

    int dst = (r >> 4) * 4096 + (lane >> 3) * 512 + ((lane >> 1) & 3) * 128
            + (r & 15) * 8 + (lane & 1) * 4;

    union { __hip_bfloat16 h[4]; uint2 u; } pk;
    pk.h[0] = __float2bfloat16(a.x * si);
    pk.h[1] = __float2bfloat16(a.y * si);
    pk.h[2] = __float2bfloat16(a.z * si);
    pk.h[3] = __float2bfloat16(a.w * si);
    *(uint2*)(zt + dst) = pk.u;                       // z_i row r
    pk.h[0] = __float2bfloat16(b.x * sj);
    pk.h[1] = __float2bfloat16(b.y * sj);
    pk.h[2] = __float2bfloat16(b.z * sj);
    pk.h[3] = __float2bfloat16(b.w * sj);
    *(uint2*)(zt + dst + 128 * 4096) = pk.u;          // z_j row r+2048

    if (lane == 0) pos[r] = sd * si * sj;
    if (blockIdx.x == 0 && t == 0) out[0] = 0.0f;     // loss accumulator
}

// ---------------------------------------------------------------------------
// K2: bf16 MFMA over the 528 upper-triangle 128x128 tiles, LDS-STAGED.
// K split into 4 chunks of 64 (2 MFMA K-steps each). Per chunk the 4 waves
// cooperatively stage A-panel (16 KB) + B-panel (16 KB) into LDS, double-
// buffered (64 KB). T14 split: next-chunk global loads issue BEFORE compute
// (latency hides under MFMA), ds_writes land AFTER, then __syncthreads.
// LDS bytes = exactly the bytes each lane loaded from global in round 6,
// same MFMA order -> bit-identical accumulators.
// Waves w=0,1 stage A row-blocks 0-3 / 4-7; w=2,3 stage B likewise.
// part[] slot scheme unchanged (round-2 comment).
// Fragment layouts (verified m89/m91): A[m=lane&15][k=quad*8+j],
// B[k=quad*8+j][n=lane&15], C/D: col=lane&15, row=quad*4+reg.
// ---------------------------------------------------------------------------
#define MFMA1(Av, Bv, m, n) \
    acc[m][n] = __builtin_amdgcn_mfma_f32_16x16x32_bf16(Av, Bv, acc[m][n], 0, 0, 0);

#define MFMA_ROW(Av, B0v, B1v, B2v, B3v, m) \
    MFMA1(Av, B0v, m, 0) MFMA1(Av, B1v, m, 1) \
    MFMA1(Av, B2v, m, 2) MFMA1(Av, B3v, m, 3)

#define MMSTEP(A0v, A1v, A2v, A3v, B0v, B1v, B2v, B3v) \
    MFMA_ROW(A0v, B0v, B1v, B2v, B3v, 0) \
    MFMA_ROW(A1v, B0v, B1v, B2v, B3v, 1) \
    MFMA_ROW(A2v, B0v, B1v, B2v, B3v, 2) \
    MFMA_ROW(A3v, B0v, B1v, B2v, B3v, 3)

#define SB __builtin_amdgcn_sched_barrier(0);

// Issue the 8 staging loads for chunk c into named regs G0..G7.
// stg_base already includes the wave's panel + row-block-pair + lane offset.
#define SLD(c) \
    G0 = *(const bf16x8*)(stg_base + 0 * 4096 + (2*(c)+0) * 512); \
    G1 = *(const bf16x8*)(stg_base + 0 * 4096 + (2*(c)+1) * 512); \
    G2 = *(const bf16x8*)(stg_base + 1 * 4096 + (2*(c)+0) * 512); \
    G3 = *(const bf16x8*)(stg_base + 1 * 4096 + (2*(c)+1) * 512); \
    G4 = *(const bf16x8*)(stg_base + 2 * 4096 + (2*(c)+0) * 512); \
    G5 = *(const bf16x8*)(stg_base + 2 * 4096 + (2*(c)+1) * 512); \
    G6 = *(const bf16x8*)(stg_base + 3 * 4096 + (2*(c)+0) * 512); \
    G7 = *(const bf16x8*)(stg_base + 3 * 4096 + (2*(c)+1) * 512);

// Write G0..G7 to LDS buffer bs (wave's 8 pieces at p0 = w*8).
#define DSW(bs) \
    *(bf16x8*)&lds[(bs)*16384 + (p0+0)*512 + l8] = G0; \
    *(bf16x8*)&lds[(bs)*16384 + (p0+1)*512 + l8] = G1; \
    *(bf16x8*)&lds[(bs)*16384 + (p0+2)*512 + l8] = G2; \
    *(bf16x8*)&lds[(bs)*16384 + (p0+3)*512 + l8] = G3; \
    *(bf16x8*)&lds[(bs)*16384 + (p0+4)*512 + l8] = G4; \
    *(bf16x8*)&lds[(bs)*16384 + (p0+5)*512 + l8] = G5; \
    *(bf16x8*)&lds[(bs)*16384 + (p0+6)*512 + l8] = G6; \
    *(bf16x8*)&lds[(bs)*16384 + (p0+7)*512 + l8] = G7;

// One K-sub-step (sl = 0/1) of chunk in buffer bs: 8 ds_read_b128 + 16 MFMA.
#define CSTEP(bs, sl) \
    { \
        bf16x8 fa0 = *(const bf16x8*)&lds[(bs)*16384 + ((wm4+0)*2+(sl))*512 + l8]; \
        bf16x8 fa1 = *(const bf16x8*)&lds[(bs)*16384 + ((wm4+1)*2+(sl))*512 + l8]; \
        bf16x8 fa2 = *(const bf16x8*)&lds[(bs)*16384 + ((wm4+2)*2+(sl))*512 + l8]; \
        bf16x8 fa3 = *(const bf16x8*)&lds[(bs)*16384 + ((wm4+3)*2+(sl))*512 + l8]; \
        bf16x8 fb0 = *(const bf16x8*)&lds[(bs)*16384 + 8192 + ((wn4+0)*2+(sl))*512 + l8]; \
        bf16x8 fb1 = *(const bf16x8*)&lds[(bs)*16384 + 8192 + ((wn4+1)*2+(sl))*512 + l8]; \
        bf16x8 fb2 = *(const bf16x8*)&lds[(bs)*16384 + 8192 + ((wn4+2)*2+(sl))*512 + l8]; \
        bf16x8 fb3 = *(const bf16x8*)&lds[(bs)*16384 + 8192 + ((wn4+3)*2+(sl))*512 + l8]; \
        MMSTEP(fa0, fa1, fa2, fa3, fb0, fb1, fb2, fb3) \
    }

#define COMPUTE(bs) CSTEP(bs, 0) CSTEP(bs, 1)

__global__ __launch_bounds__(256, 2) void simexp_kernel(
    const short* __restrict__ zt, float* __restrict__ part)
{
    __shared__ short lds[2 * 16384];            // 2 x 32 KB chunk buffers

    // Decode linear triangle index -> (bx, by), bx <= by.
    int id = blockIdx.x;
    int by = (int)((sqrtf(8.0f * (float)id + 1.0f) - 1.0f) * 0.5f);
    while ((by + 1) * (by + 2) / 2 <= id) ++by;   // fix float rounding
    while (by * (by + 1) / 2 > id) --by;
    int bx = id - by * (by + 1) / 2;

    int t = threadIdx.x;
    int w = t >> 6, lane = t & 63;
    int quad = lane >> 4, c16 = lane & 15;
    int wm = w >> 1, wn = w & 1;
    int wm4 = wm * 4, wn4 = wn * 4;
    int l8 = lane * 8;
    int p0 = w * 8;
    int rbase = bx * 128 + wm * 64;
    int jbase = by * 128 + wn * 64;

    // Staging source base for this wave: waves 0,1 -> A panel (row-blocks
    // bx*8 + {0-3, 4-7}); waves 2,3 -> B panel (by*8 + {0-3, 4-7}).
    const short* stg_base = zt
        + (size_t)((w < 2 ? bx : by) * 8 + (w & 1) * 4) * 4096 + l8;

    f32x4 acc[4][4];
    #pragma unroll
    for (int mt = 0; mt < 4; ++mt)
        #pragma unroll
        for (int nt = 0; nt < 4; ++nt)
            acc[mt][nt] = (f32x4){0.f, 0.f, 0.f, 0.f};

    bf16x8 G0, G1, G2, G3, G4, G5, G6, G7;

    // Prologue: stage chunk 0 into buf 0.
    SLD(0)
    DSW(0)
    __syncthreads();
    // c = 0
    SLD(1) SB
    COMPUTE(0) SB
    DSW(1)
    __syncthreads();
    // c = 1
    SLD(2) SB
    COMPUTE(1) SB
    DSW(0)
    __syncthreads();
    // c = 2
    SLD(3) SB
    COMPUTE(0)  /* buf0 holds chunk 2 */ SB
    DSW(1)
    __syncthreads();
    // c = 3
    COMPUTE(1)  /* buf1 holds chunk 3 */

    // Epilogue. Row of acc[mt][nt][rg] = rbase+mt*16+quad*4+rg,
    // col = jbase+nt*16+c16.
    float rsum[4][4];
    #pragma unroll
    for (int mt = 0; mt < 4; ++mt)
        #pragma unroll
        for (int rg = 0; rg < 4; ++rg) rsum[mt][rg] = 0.f;

    if (bx == by) {
        // Diagonal block: mask r==j, row-sums only.
        #pragma unroll
        for (int mt = 0; mt < 4; ++mt) {
            #pragma unroll
            for (int nt = 0; nt < 4; ++nt) {
                int j = jbase + nt * 16 + c16;
                #pragma unroll
                for (int rg = 0; rg < 4; ++rg) {
                    int r = rbase + mt * 16 + quad * 4 + rg;
                    float e = __expf(2.0f * acc[mt][nt][rg]);
                    rsum[mt][rg] += (r == j) ? 0.f : e;
                }
            }
        }
    } else {
        // Off-diagonal: no diagonal possible; row-sums AND col-sums.
        float csum[4] = {0.f, 0.f, 0.f, 0.f};
        #pragma unroll
        for (int mt = 0; mt < 4; ++mt) {
            #pragma unroll
            for (int nt = 0; nt < 4; ++nt) {
                #pragma unroll
                for (int rg = 0; rg < 4; ++rg) {
                    float e = __expf(2.0f * acc[mt][nt][rg]);
                    rsum[mt][rg] += e;
                    csum[nt] += e;
                }
            }
        }
        // col c16 of tile nt: sum the 4 quads; quad 0 writes its slot.
        #pragma unroll
        for (int nt = 0; nt < 4; ++nt) {
            float v = csum[nt];
            v += __shfl_xor(v, 16, 64);
            v += __shfl_xor(v, 32, 64);
            if (quad == 0)
                part[(size_t)(by * 128 + wn * 64 + nt * 16 + c16) * 64
                     + 2 * bx + wm] = v;
        }
    }

    // Row-sums: reduce the 16 col-lanes of each quad; c16==0 writes its slot.
    #pragma unroll
    for (int mt = 0; mt < 4; ++mt) {
        #pragma unroll
        for (int rg = 0; rg < 4; ++rg) {
            float v = rsum[mt][rg];
            v += __shfl_xor(v, 1, 64);
            v += __shfl_xor(v, 2, 64);
            v += __shfl_xor(v, 4, 64);
            v += __shfl_xor(v, 8, 64);
            if (c16 == 0)
                part[(size_t)(rbase + mt * 16 + quad * 4 + rg) * 64
                     + 2 * by + wn] = v;
        }
    }
}

// ---------------------------------------------------------------------------
// K3: 32 blocks x 128 threads. Block s, thread t owns row r = s*128+t:
// den_r = sum of its 64 partials (256 B contiguous), then
// loss_r = log(den_r) - 2*pos[r mod 2048]. Block-reduce, one atomicAdd of
// the scaled partial into out[0] (32 atomics total; out zeroed by K1).
// ---------------------------------------------------------------------------
__global__ __launch_bounds__(128) void redloss_kernel(
    const float* __restrict__ part, const float* __restrict__ pos,
    float* __restrict__ out)
{
    int s = blockIdx.x, t = threadIdx.x;
    int r = s * 128 + t;
    const float4* p = (const float4*)(part + ((size_t)r << 6));
    float sum = 0.f;
    #pragma unroll
    for (int i = 0; i < 16; ++i) {
        float4 v = p[i];
        sum += v.x + v.y + v.z + v.w;
    }
    float val = logf(sum) - 2.0f * pos[r & (NB - 1)];
    #pragma unroll
    for (int off = 32; off >= 1; off >>= 1) val += __shfl_xor(val, off, 64);
    __shared__ float red[2];
    if ((t & 63) == 0) red[t >> 6] = val;
    __syncthreads();
    if (t == 0)
        atomicAdd(out, (red[0] + red[1]) * (1.0f / (float)TWO_N));
}

// ---------------------------------------------------------------------------
extern "C" void kernel_launch(void* const* d_in, const int* in_sizes, int n_in,
                              void* d_out, int out_size, void* d_ws, size_t ws_size,
                              hipStream_t stream)
{
    const float* emb_i = (const float*)d_in[0];
    const float* emb_j = (const float*)d_in[1];
    float* out = (float*)d_out;

    short* zt = (short*)d_ws;                             // 4096*256 bf16 = 2 MB (tiled)
    float* part = (float*)((char*)d_ws + (size_t)TWO_N * DIM * sizeof(short));
    // part: 4096 rows x 64 partials = 1 MB
    float* pos = part + (size_t)TWO_N * 64;               // 2048 f32

    nrm_kernel<<<NB / 4, 256, 0, stream>>>(emb_i, emb_j, zt, pos, out);
    simexp_kernel<<<NTILES, 256, 0, stream>>>(zt, part);
    redloss_kernel<<<NT1D, 128, 0, stream>>>(part, pos, out);
}